// Round 3
// baseline (716.651 us; speedup 1.0000x reference)
//
#include <hip/hip_runtime.h>

// Problem constants (fixed instance)
constexpr int N_NODES = 32;
constexpr int D = 96;
constexpr int E_EDGES = 256;

constexpr int F_ELEMS = 4 * 32 * 4 * 47;

__device__ __forceinline__ int rfl(int x) { return __builtin_amdgcn_readfirstlane(x); }

// ---------------- Kernel 0: per-node conv1 feature tables ----------------
// F[c][node][o][i] = sum_k w1[o][c][k] * emb[node][2i+k]
__global__ void precompute_F(const float* __restrict__ emb, const float* __restrict__ w1,
                             float* __restrict__ F) {
    int idx = blockIdx.x * blockDim.x + threadIdx.x;  // 24064 total, grid exact
    int i = idx % 47;
    int o = (idx / 47) % 4;
    int node = (idx / (47 * 4)) % 32;
    int c = idx / (47 * 4 * 32);
    float acc = 0.f;
#pragma unroll
    for (int k = 0; k < 3; k++) acc += w1[(o * 4 + c) * 3 + k] * emb[node * D + 2 * i + k];
    F[idx] = acc;
}

// ---------------- Kernel 1: the 254k-sample CNN+MLP ----------------
// grid = 4096 blocks: block b -> pair p = b>>2, edge chunk e0 = (b&3)*64
// 256 threads: conv phase thread=(sample=tid>>2, ch=tid&3); fc phase (wave=tid>>6, lane=sample)
// LDS 70.7 KB -> 2 blocks/CU; fc2/fc3 chunk = 128 so each a1t ds_read feeds 32 FMAs.
__global__ __launch_bounds__(256, 2)
void mlp_kernel(const float* __restrict__ F, const int* __restrict__ edges,
                const float* __restrict__ b1v,
                const float* __restrict__ w2, const float* __restrict__ b2,
                const float* __restrict__ w3, const float* __restrict__ b3,
                const float* __restrict__ fc1_w, const float* __restrict__ fc1_b,
                const float* __restrict__ fc2_w, const float* __restrict__ fc2_b,
                const float* __restrict__ fc3_w, const float* __restrict__ fc3_b,
                const float* __restrict__ fc4_w, const float* __restrict__ fc4_b,
                float* __restrict__ preds) {
    // LDS (floats):
    //   region A [0..8448): h1t [23][4][64] then h2t at 5888: [10][4][64]
    //                       a1t [128][64] (8192) aliases A after conv phase
    //   flat_t  [8448..9472): [16][64]; part[256] aliases flat_t after fc1
    //   h2c     [9472..17664): [128][64]
    __shared__ float smem[17664];
    float* h1t = smem;
    float* h2t = smem + 5888;
    float* a1t = smem;            // alias of conv region
    float* flat_t = smem + 8448;  // [f<16][sample<64]
    float* part = smem + 8448;    // alias of flat_t (dead by then)
    float* h2c = smem + 9472;     // [j<128][sample<64]

    const int tid = threadIdx.x;
    const int p = blockIdx.x >> 2;
    const int e0 = (blockIdx.x & 3) * 64;
    const int s = p >> 5, t = p & 31;
    if (s == t) return;  // contributes exactly 0 to rbc

    // ---- conv1 (table sum) + pool ----
    {
        const int sample = tid >> 2, o = tid & 3;
        const int e = e0 + sample;
        const int u = edges[2 * e], v = edges[2 * e + 1];
        const float* F0 = F + ((0 * 32 + s) * 4 + o) * 47;
        const float* F1 = F + ((1 * 32 + t) * 4 + o) * 47;
        const float* F2 = F + ((2 * 32 + u) * 4 + o) * 47;
        const float* F3 = F + ((3 * 32 + v) * 4 + o) * 47;
        const float bb = b1v[o];
        float pre[46];
#pragma unroll
        for (int i = 0; i < 46; i++) {  // element 46 is dropped by the pool
            float x = F0[i] + F1[i] + F2[i] + F3[i] + bb;
            pre[i] = fmaxf(x, 0.f);
        }
#pragma unroll
        for (int j = 0; j < 23; j++)
            h1t[(j * 4 + o) * 64 + sample] = fmaxf(pre[2 * j], pre[2 * j + 1]);
    }
    __syncthreads();
    // ---- conv2 + pool (sliding-window register reuse of h1t) ----
    {
        const int sample = tid >> 2, o = tid & 3;
        float wreg[12];
#pragma unroll
        for (int q = 0; q < 12; q++) wreg[q] = w2[o * 12 + q];
        const float bb = b2[o];
        float win[4][3];  // win[c][(i+k)%3] holds h1t position i+k
#pragma unroll
        for (int c = 0; c < 4; c++) {
            win[c][0] = h1t[(0 * 4 + c) * 64 + sample];
            win[c][1] = h1t[(1 * 4 + c) * 64 + sample];
        }
        float pre[20];
#pragma unroll
        for (int i = 0; i < 20; i++) {  // element 20 dropped by pool
#pragma unroll
            for (int c = 0; c < 4; c++)
                win[c][(i + 2) % 3] = h1t[((i + 2) * 4 + c) * 64 + sample];
            float acc = bb;
#pragma unroll
            for (int c = 0; c < 4; c++)
#pragma unroll
                for (int k = 0; k < 3; k++)
                    acc = fmaf(wreg[c * 3 + k], win[c][(i + k) % 3], acc);
            pre[i] = fmaxf(acc, 0.f);
        }
#pragma unroll
        for (int j = 0; j < 10; j++)
            h2t[(j * 4 + o) * 64 + sample] = fmaxf(pre[2 * j], pre[2 * j + 1]);
    }
    __syncthreads();
    // ---- conv3 + pool + flatten (sliding window) ----
    {
        const int sample = tid >> 2, o = tid & 3;
        float wreg[12];
#pragma unroll
        for (int q = 0; q < 12; q++) wreg[q] = w3[o * 12 + q];
        const float bb = b3[o];
        float win[4][3];
#pragma unroll
        for (int c = 0; c < 4; c++) {
            win[c][0] = h2t[(0 * 4 + c) * 64 + sample];
            win[c][1] = h2t[(1 * 4 + c) * 64 + sample];
        }
        float pre[8];
#pragma unroll
        for (int i = 0; i < 8; i++) {
#pragma unroll
            for (int c = 0; c < 4; c++)
                win[c][(i + 2) % 3] = h2t[((i + 2) * 4 + c) * 64 + sample];
            float acc = bb;
#pragma unroll
            for (int c = 0; c < 4; c++)
#pragma unroll
                for (int k = 0; k < 3; k++)
                    acc = fmaf(wreg[c * 3 + k], win[c][(i + k) % 3], acc);
            pre[i] = fmaxf(acc, 0.f);
        }
#pragma unroll
        for (int l = 0; l < 4; l++)
            flat_t[(o * 4 + l) * 64 + sample] = fmaxf(pre[2 * l], pre[2 * l + 1]);
    }
    __syncthreads();
    // ---- fc1: 16 -> 128, wave owns 32 j's, lane=sample ----
    {
        const int lane = tid & 63, wave = tid >> 6;
        const int j0 = rfl(wave * 32);
        float acc[32];
        const float* bp = fc1_b + j0;
#pragma unroll
        for (int jj = 0; jj < 32; jj++) acc[jj] = bp[jj];
#pragma unroll
        for (int kk = 0; kk < 16; kk++) {
            float a = flat_t[kk * 64 + lane];
            const float* wr = fc1_w + kk * 128 + j0;
#pragma unroll
            for (int jj = 0; jj < 32; jj++) acc[jj] = fmaf(a, wr[jj], acc[jj]);
        }
#pragma unroll
        for (int jj = 0; jj < 32; jj++)
            a1t[(j0 + jj) * 64 + lane] = fmaxf(acc[jj], 0.f);
    }
    __syncthreads();
    // ---- fc2 (128->256) fused with fc3 (256->128), 128-wide chunks ----
    {
        const int lane = tid & 63, wave = tid >> 6;
        const int i0 = rfl(wave * 32);
        float acc3[32];
        const float* b3p = fc3_b + i0;
#pragma unroll
        for (int ii = 0; ii < 32; ii++) acc3[ii] = b3p[ii];
        for (int chunk = 0; chunk < 2; chunk++) {
            const int jw = rfl(chunk * 128 + wave * 32);
            float acc2[32];
            const float* b2p = fc2_b + jw;
#pragma unroll
            for (int jj = 0; jj < 32; jj++) acc2[jj] = b2p[jj];
#pragma unroll 4
            for (int k = 0; k < 128; k++) {
                float a = a1t[k * 64 + lane];
                const float* wr = fc2_w + k * 256 + jw;
#pragma unroll
                for (int jj = 0; jj < 32; jj++) acc2[jj] = fmaf(a, wr[jj], acc2[jj]);
            }
#pragma unroll
            for (int jj = 0; jj < 32; jj++)
                h2c[(wave * 32 + jj) * 64 + lane] = fmaxf(acc2[jj], 0.f);
            __syncthreads();
            const int J0 = rfl(chunk * 128);
#pragma unroll 4
            for (int jj = 0; jj < 128; jj++) {
                float a = h2c[jj * 64 + lane];
                const float* wr = fc3_w + (J0 + jj) * 128 + i0;
#pragma unroll
                for (int ii = 0; ii < 32; ii++) acc3[ii] = fmaf(a, wr[ii], acc3[ii]);
            }
            __syncthreads();
        }
        // ---- fc4 partial dot over this wave's 32 i's ----
        float partial = 0.f;
        const float* w4 = fc4_w + i0;
#pragma unroll
        for (int ii = 0; ii < 32; ii++) partial += fmaxf(acc3[ii], 0.f) * w4[ii];
        part[wave * 64 + lane] = partial;
    }
    __syncthreads();
    if (tid < 64) {
        float pred = part[tid] + part[64 + tid] + part[128 + tid] + part[192 + tid] + fc4_b[0];
        preds[p * 256 + e0 + tid] = pred;
    }
}

// ---------------- Kernel 2: 3-step propagation ----------------
__global__ void prop_kernel(const int* __restrict__ edges,
                            const float* __restrict__ preds,
                            float* __restrict__ rbc) {
    const int p = blockIdx.x;
    const int s = p >> 5, t = p & 31;
    if (s == t) return;
    __shared__ float x[32], xn[32], racc[32];
    const int tid = threadIdx.x;
    if (tid < 32) { x[tid] = (tid == s) ? 1.f : 0.f; racc[tid] = 0.f; }
    const int u = edges[2 * tid], v = edges[2 * tid + 1];
    const float pr = preds[p * 256 + tid];
    for (int step = 0; step < 3; step++) {
        if (tid < 32) xn[tid] = 0.f;
        __syncthreads();
        atomicAdd(&xn[v], x[u] * pr);
        __syncthreads();
        if (tid < 32) { racc[tid] += xn[tid]; x[tid] = xn[tid]; }
        __syncthreads();
    }
    if (tid < 32) atomicAdd(&rbc[tid], racc[tid]);
}

// ---------------- Kernel 3: normalize ----------------
__global__ void norm_kernel(const float* __restrict__ rbc, float* __restrict__ out) {
    int tid = threadIdx.x;
    if (tid < 32) {
        float ssum = 0.f;
#pragma unroll
        for (int j = 0; j < 32; j++) ssum += rbc[j];
        out[tid] = rbc[tid] / ssum;
    }
}

extern "C" void kernel_launch(void* const* d_in, const int* in_sizes, int n_in,
                              void* d_out, int out_size, void* d_ws, size_t ws_size,
                              hipStream_t stream) {
    const float* emb = (const float*)d_in[0];
    const int* edges = (const int*)d_in[1];
    const float* w1 = (const float*)d_in[2];
    const float* b1 = (const float*)d_in[3];
    const float* w2 = (const float*)d_in[4];
    const float* b2 = (const float*)d_in[5];
    const float* w3 = (const float*)d_in[6];
    const float* b3 = (const float*)d_in[7];
    const float* fc1_w = (const float*)d_in[8];
    const float* fc1_b = (const float*)d_in[9];
    const float* fc2_w = (const float*)d_in[10];
    const float* fc2_b = (const float*)d_in[11];
    const float* fc3_w = (const float*)d_in[12];
    const float* fc3_b = (const float*)d_in[13];
    const float* fc4_w = (const float*)d_in[14];
    const float* fc4_b = (const float*)d_in[15];

    float* ws = (float*)d_ws;
    float* F = ws;                            // 24064 floats
    float* preds = ws + F_ELEMS;              // 262144 floats
    float* rbc = ws + F_ELEMS + 1024 * 256;   // 32 floats
    float* out = (float*)d_out;

    precompute_F<<<dim3(94), dim3(256), 0, stream>>>(emb, w1, F);
    mlp_kernel<<<dim3(4096), dim3(256), 0, stream>>>(
        F, edges, b1, w2, b2, w3, b3, fc1_w, fc1_b, fc2_w, fc2_b, fc3_w, fc3_b,
        fc4_w, fc4_b, preds);
    (void)hipMemsetAsync(rbc, 0, 32 * sizeof(float), stream);
    prop_kernel<<<dim3(1024), dim3(256), 0, stream>>>(edges, preds, rbc);
    norm_kernel<<<dim3(1), dim3(64), 0, stream>>>(rbc, out);
}

// Round 4
// 238.127 us; speedup vs baseline: 3.0095x; 3.0095x over previous
//
#include <hip/hip_runtime.h>

// ---- fixed problem instance ----
constexpr int F_ELEMS = 4 * 32 * 4 * 47;          // conv1 tables
constexpr int PREDS_OFF = F_ELEMS;                // float offset in ws
constexpr int RBC_OFF = PREDS_OFF + 1024 * 256;
constexpr int W2P_OFF = RBC_OFF + 32;             // fc2 packed weights (65536 shorts = 32768 floats)
constexpr int W3P_OFF = W2P_OFF + 32768;          // fc3 packed weights

typedef __attribute__((ext_vector_type(8))) short short8;
typedef __attribute__((ext_vector_type(4))) float f32x4;

__device__ __forceinline__ int rfl(int x) { return __builtin_amdgcn_readfirstlane(x); }
__device__ __forceinline__ unsigned short f2bf(float x) {  // round-to-nearest-even bf16
    unsigned u = __float_as_uint(x);
    u += 0x7FFF + ((u >> 16) & 1);
    return (unsigned short)(u >> 16);
}
__device__ __forceinline__ float bf2f(unsigned short h) {
    return __uint_as_float(((unsigned)h) << 16);
}

// ---------------- Kernel 0: per-node conv1 feature tables ----------------
__global__ void precompute_F(const float* __restrict__ emb, const float* __restrict__ w1,
                             float* __restrict__ F) {
    int idx = blockIdx.x * blockDim.x + threadIdx.x;  // 24064 total
    int i = idx % 47;
    int o = (idx / 47) % 4;
    int node = (idx / (47 * 4)) % 32;
    int c = idx / (47 * 4 * 32);
    float acc = 0.f;
#pragma unroll
    for (int k = 0; k < 3; k++) acc += w1[(o * 4 + c) * 3 + k] * emb[node * 96 + 2 * i + k];
    F[idx] = acc;
}

// ---------------- Kernel 0b: swizzle fc2/fc3 weights to MFMA B-frag layout, bf16 hi/lo ----
// W2p: frag(nt,ks,term): (((nt*4+ks)*2+term)*64+lane)*8+j ; B[k][n], k=ks*32+(lane>>4)*8+j, n=nt*16+(lane&15)
__global__ void prep_weights(const float* __restrict__ fc2_w, const float* __restrict__ fc3_w,
                             unsigned short* __restrict__ W2p, unsigned short* __restrict__ W3p) {
    int t = blockIdx.x * 256 + threadIdx.x;  // 131072 total
    if (t < 65536) {
        int j = t & 7, lane = (t >> 3) & 63, term = (t >> 9) & 1, ks = (t >> 10) & 3, nt = t >> 12;
        int k = ks * 32 + (lane >> 4) * 8 + j, n = nt * 16 + (lane & 15);
        float w = fc2_w[k * 256 + n];
        unsigned short hi = f2bf(w);
        W2p[t] = (term == 0) ? hi : f2bf(w - bf2f(hi));
    } else {
        int t3 = t - 65536;
        int j = t3 & 7, lane = (t3 >> 3) & 63, term = (t3 >> 9) & 1, ks = (t3 >> 10) & 7, nt = t3 >> 13;
        int k = ks * 32 + (lane >> 4) * 8 + j, n = nt * 16 + (lane & 15);
        float w = fc3_w[k * 128 + n];
        unsigned short hi = f2bf(w);
        W3p[t3] = (term == 0) ? hi : f2bf(w - bf2f(hi));
    }
}

// ---------------- Kernel 1: conv (VALU) + fc1 (VALU) + fc2/fc3 (MFMA bf16 hi/lo) ----------------
// block: 64 samples (pair p, edge chunk e0). 4 waves. M=64 (4 tiles), waves split N.
__global__ __launch_bounds__(256, 2)
void mlp_kernel(const float* __restrict__ F, const int* __restrict__ edges,
                const float* __restrict__ b1v,
                const float* __restrict__ w2, const float* __restrict__ b2,
                const float* __restrict__ w3, const float* __restrict__ b3,
                const float* __restrict__ fc1_w, const float* __restrict__ fc1_b,
                const float* __restrict__ fc2_b,
                const float* __restrict__ fc3_b,
                const float* __restrict__ fc4_w, const float* __restrict__ fc4_b,
                const unsigned short* __restrict__ W2p, const unsigned short* __restrict__ W3p,
                float* __restrict__ preds) {
    // LDS (floats): [0,8448) conv h1t/h2t, aliased later by X3 (64x264 shorts = 33792 B exact)
    //               [8448,9472) flat_t fp32 [16][64]; part[256] aliases it
    //               [9472,13824) X2 bf16 [64][136]
    __shared__ __align__(16) float smem[13824];
    float* h1t = smem;
    float* h2t = smem + 5888;
    float* flat_t = smem + 8448;
    float* part = smem + 8448;
    unsigned short* X3 = (unsigned short*)smem;            // [64][264] bf16, rowlen 264
    unsigned short* X2 = (unsigned short*)(smem + 9472);   // [64][136] bf16, rowlen 136

    const int tid = threadIdx.x;
    const int p = blockIdx.x >> 2;
    const int e0 = (blockIdx.x & 3) * 64;
    const int s = p >> 5, t = p & 31;
    if (s == t) return;  // contributes exactly 0

    // ---- conv1 (table sum) + pool ----
    {
        const int sample = tid >> 2, o = tid & 3;
        const int e = e0 + sample;
        const int u = edges[2 * e], v = edges[2 * e + 1];
        const float* F0 = F + ((0 * 32 + s) * 4 + o) * 47;
        const float* F1 = F + ((1 * 32 + t) * 4 + o) * 47;
        const float* F2 = F + ((2 * 32 + u) * 4 + o) * 47;
        const float* F3 = F + ((3 * 32 + v) * 4 + o) * 47;
        const float bb = b1v[o];
        float pre[46];
#pragma unroll
        for (int i = 0; i < 46; i++) {
            float x = F0[i] + F1[i] + F2[i] + F3[i] + bb;
            pre[i] = fmaxf(x, 0.f);
        }
#pragma unroll
        for (int j = 0; j < 23; j++)
            h1t[(j * 4 + o) * 64 + sample] = fmaxf(pre[2 * j], pre[2 * j + 1]);
    }
    __syncthreads();
    // ---- conv2 + pool (sliding window) ----
    {
        const int sample = tid >> 2, o = tid & 3;
        float wreg[12];
#pragma unroll
        for (int q = 0; q < 12; q++) wreg[q] = w2[o * 12 + q];
        const float bb = b2[o];
        float win[4][3];
#pragma unroll
        for (int c = 0; c < 4; c++) {
            win[c][0] = h1t[(0 * 4 + c) * 64 + sample];
            win[c][1] = h1t[(1 * 4 + c) * 64 + sample];
        }
        float pre[20];
#pragma unroll
        for (int i = 0; i < 20; i++) {
#pragma unroll
            for (int c = 0; c < 4; c++)
                win[c][(i + 2) % 3] = h1t[((i + 2) * 4 + c) * 64 + sample];
            float acc = bb;
#pragma unroll
            for (int c = 0; c < 4; c++)
#pragma unroll
                for (int k = 0; k < 3; k++)
                    acc = fmaf(wreg[c * 3 + k], win[c][(i + k) % 3], acc);
            pre[i] = fmaxf(acc, 0.f);
        }
#pragma unroll
        for (int j = 0; j < 10; j++)
            h2t[(j * 4 + o) * 64 + sample] = fmaxf(pre[2 * j], pre[2 * j + 1]);
    }
    __syncthreads();
    // ---- conv3 + pool + flatten ----
    {
        const int sample = tid >> 2, o = tid & 3;
        float wreg[12];
#pragma unroll
        for (int q = 0; q < 12; q++) wreg[q] = w3[o * 12 + q];
        const float bb = b3[o];
        float win[4][3];
#pragma unroll
        for (int c = 0; c < 4; c++) {
            win[c][0] = h2t[(0 * 4 + c) * 64 + sample];
            win[c][1] = h2t[(1 * 4 + c) * 64 + sample];
        }
        float pre[8];
#pragma unroll
        for (int i = 0; i < 8; i++) {
#pragma unroll
            for (int c = 0; c < 4; c++)
                win[c][(i + 2) % 3] = h2t[((i + 2) * 4 + c) * 64 + sample];
            float acc = bb;
#pragma unroll
            for (int c = 0; c < 4; c++)
#pragma unroll
                for (int k = 0; k < 3; k++)
                    acc = fmaf(wreg[c * 3 + k], win[c][(i + k) % 3], acc);
            pre[i] = fmaxf(acc, 0.f);
        }
#pragma unroll
        for (int l = 0; l < 4; l++)
            flat_t[(o * 4 + l) * 64 + sample] = fmaxf(pre[2 * l], pre[2 * l + 1]);
    }
    __syncthreads();
    // ---- fc1: 16 -> 128 (VALU), output bf16 to X2[m][k] ----
    {
        const int lane = tid & 63, wave = tid >> 6;
        const int j0 = rfl(wave * 32);
        float acc[32];
        const float* bp = fc1_b + j0;
#pragma unroll
        for (int jj = 0; jj < 32; jj++) acc[jj] = bp[jj];
#pragma unroll
        for (int kk = 0; kk < 16; kk++) {
            float a = flat_t[kk * 64 + lane];
            const float* wr = fc1_w + kk * 128 + j0;
#pragma unroll
            for (int jj = 0; jj < 32; jj++) acc[jj] = fmaf(a, wr[jj], acc[jj]);
        }
#pragma unroll
        for (int jj = 0; jj < 32; jj++)
            X2[lane * 136 + j0 + jj] = f2bf(fmaxf(acc[jj], 0.f));
    }
    __syncthreads();
    // ---- fc2: [64x128] @ [128x256], MFMA, wave w owns Ntiles 4w..4w+3 ----
    {
        const int lane = tid & 63, wave = tid >> 6;
        const int mrow = lane & 15, quad = lane >> 4;
        // A-fragments: afr[mt][ks], 16 x ds_read_b128
        short8 afr[4][4];
#pragma unroll
        for (int mt = 0; mt < 4; mt++)
#pragma unroll
            for (int ks = 0; ks < 4; ks++)
                afr[mt][ks] = *(const short8*)(X2 + (mt * 16 + mrow) * 136 + ks * 32 + quad * 8);
        f32x4 acc[4][4];  // [ntl][mt]
#pragma unroll
        for (int a = 0; a < 4; a++)
#pragma unroll
            for (int b = 0; b < 4; b++) acc[a][b] = (f32x4){0.f, 0.f, 0.f, 0.f};
        const short8* W2v = (const short8*)W2p;
#pragma unroll
        for (int ntl = 0; ntl < 4; ntl++) {
            const int nt = wave * 4 + ntl;
#pragma unroll
            for (int ks = 0; ks < 4; ks++) {
                short8 bh = W2v[((nt * 4 + ks) * 2 + 0) * 64 + lane];
                short8 bl = W2v[((nt * 4 + ks) * 2 + 1) * 64 + lane];
#pragma unroll
                for (int mt = 0; mt < 4; mt++) {
                    acc[ntl][mt] = __builtin_amdgcn_mfma_f32_16x16x32_bf16(afr[mt][ks], bh, acc[ntl][mt], 0, 0, 0);
                    acc[ntl][mt] = __builtin_amdgcn_mfma_f32_16x16x32_bf16(afr[mt][ks], bl, acc[ntl][mt], 0, 0, 0);
                }
            }
        }
        __syncthreads();  // conv region dead; X3 (alias) safe to write
        // epilogue: bias + relu -> bf16 X3[m][n]
#pragma unroll
        for (int ntl = 0; ntl < 4; ntl++) {
            const int n = (wave * 4 + ntl) * 16 + mrow;
            const float bias = fc2_b[n];
#pragma unroll
            for (int mt = 0; mt < 4; mt++)
#pragma unroll
                for (int r = 0; r < 4; r++) {
                    const int m = mt * 16 + quad * 4 + r;
                    X3[m * 264 + n] = f2bf(fmaxf(acc[ntl][mt][r] + bias, 0.f));
                }
        }
    }
    __syncthreads();
    // ---- fc3: [64x256] @ [256x128], MFMA, wave w owns Ntiles 2w,2w+1; fc4 fused ----
    {
        const int lane = tid & 63, wave = tid >> 6;
        const int mrow = lane & 15, quad = lane >> 4;
        const short8* W3v = (const short8*)W3p;
        float p4[4][4];  // [mt][r] fc4 partials
#pragma unroll
        for (int a = 0; a < 4; a++)
#pragma unroll
            for (int b = 0; b < 4; b++) p4[a][b] = 0.f;
#pragma unroll
        for (int ntl = 0; ntl < 2; ntl++) {
            const int nt = wave * 2 + ntl;
            short8 B3h[8], B3l[8];
#pragma unroll
            for (int ks = 0; ks < 8; ks++) {
                B3h[ks] = W3v[((nt * 8 + ks) * 2 + 0) * 64 + lane];
                B3l[ks] = W3v[((nt * 8 + ks) * 2 + 1) * 64 + lane];
            }
            const int n = nt * 16 + mrow;
            const float bias = fc3_b[n];
            const float w4 = fc4_w[n];
#pragma unroll
            for (int mt = 0; mt < 4; mt++) {
                f32x4 acc3 = (f32x4){0.f, 0.f, 0.f, 0.f};
#pragma unroll
                for (int ks = 0; ks < 8; ks++) {
                    short8 a3 = *(const short8*)(X3 + (mt * 16 + mrow) * 264 + ks * 32 + quad * 8);
                    acc3 = __builtin_amdgcn_mfma_f32_16x16x32_bf16(a3, B3h[ks], acc3, 0, 0, 0);
                    acc3 = __builtin_amdgcn_mfma_f32_16x16x32_bf16(a3, B3l[ks], acc3, 0, 0, 0);
                }
#pragma unroll
                for (int r = 0; r < 4; r++)
                    p4[mt][r] = fmaf(fmaxf(acc3[r] + bias, 0.f), w4, p4[mt][r]);
            }
        }
        // reduce partials across the 16 n-lanes (same m in lanes sharing quad)
#pragma unroll
        for (int mask = 1; mask < 16; mask <<= 1)
#pragma unroll
            for (int mt = 0; mt < 4; mt++)
#pragma unroll
                for (int r = 0; r < 4; r++)
                    p4[mt][r] += __shfl_xor(p4[mt][r], mask, 64);
        if ((lane & 15) == 0) {
#pragma unroll
            for (int mt = 0; mt < 4; mt++)
#pragma unroll
                for (int r = 0; r < 4; r++)
                    part[wave * 64 + mt * 16 + quad * 4 + r] = p4[mt][r];
        }
    }
    __syncthreads();
    if (tid < 64) {
        float pred = part[tid] + part[64 + tid] + part[128 + tid] + part[192 + tid] + fc4_b[0];
        preds[p * 256 + e0 + tid] = pred;
    }
}

// ---------------- Kernel 2: 3-step propagation ----------------
__global__ void prop_kernel(const int* __restrict__ edges,
                            const float* __restrict__ preds,
                            float* __restrict__ rbc) {
    const int p = blockIdx.x;
    const int s = p >> 5, t = p & 31;
    if (s == t) return;
    __shared__ float x[32], xn[32], racc[32];
    const int tid = threadIdx.x;
    if (tid < 32) { x[tid] = (tid == s) ? 1.f : 0.f; racc[tid] = 0.f; }
    const int u = edges[2 * tid], v = edges[2 * tid + 1];
    const float pr = preds[p * 256 + tid];
    for (int step = 0; step < 3; step++) {
        if (tid < 32) xn[tid] = 0.f;
        __syncthreads();
        atomicAdd(&xn[v], x[u] * pr);
        __syncthreads();
        if (tid < 32) { racc[tid] += xn[tid]; x[tid] = xn[tid]; }
        __syncthreads();
    }
    if (tid < 32) atomicAdd(&rbc[tid], racc[tid]);
}

// ---------------- Kernel 3: normalize ----------------
__global__ void norm_kernel(const float* __restrict__ rbc, float* __restrict__ out) {
    int tid = threadIdx.x;
    if (tid < 32) {
        float ssum = 0.f;
#pragma unroll
        for (int j = 0; j < 32; j++) ssum += rbc[j];
        out[tid] = rbc[tid] / ssum;
    }
}

extern "C" void kernel_launch(void* const* d_in, const int* in_sizes, int n_in,
                              void* d_out, int out_size, void* d_ws, size_t ws_size,
                              hipStream_t stream) {
    const float* emb = (const float*)d_in[0];
    const int* edges = (const int*)d_in[1];
    const float* w1 = (const float*)d_in[2];
    const float* b1 = (const float*)d_in[3];
    const float* w2 = (const float*)d_in[4];
    const float* b2 = (const float*)d_in[5];
    const float* w3 = (const float*)d_in[6];
    const float* b3 = (const float*)d_in[7];
    const float* fc1_w = (const float*)d_in[8];
    const float* fc1_b = (const float*)d_in[9];
    const float* fc2_w = (const float*)d_in[10];
    const float* fc2_b = (const float*)d_in[11];
    const float* fc3_w = (const float*)d_in[12];
    const float* fc3_b = (const float*)d_in[13];
    const float* fc4_w = (const float*)d_in[14];
    const float* fc4_b = (const float*)d_in[15];

    float* ws = (float*)d_ws;
    float* F = ws;
    float* preds = ws + PREDS_OFF;
    float* rbc = ws + RBC_OFF;
    unsigned short* W2p = (unsigned short*)(ws + W2P_OFF);
    unsigned short* W3p = (unsigned short*)(ws + W3P_OFF);
    float* out = (float*)d_out;

    precompute_F<<<dim3(94), dim3(256), 0, stream>>>(emb, w1, F);
    prep_weights<<<dim3(512), dim3(256), 0, stream>>>(fc2_w, fc3_w, W2p, W3p);
    mlp_kernel<<<dim3(4096), dim3(256), 0, stream>>>(
        F, edges, b1, w2, b2, w3, b3, fc1_w, fc1_b, fc2_b, fc3_b,
        fc4_w, fc4_b, W2p, W3p, preds);
    (void)hipMemsetAsync(rbc, 0, 32 * sizeof(float), stream);
    prop_kernel<<<dim3(1024), dim3(256), 0, stream>>>(edges, preds, rbc);
    norm_kernel<<<dim3(1), dim3(64), 0, stream>>>(rbc, out);
}

// Round 5
// 226.991 us; speedup vs baseline: 3.1572x; 1.0491x over previous
//
#include <hip/hip_runtime.h>

// ---- fixed problem instance ----
constexpr int F_ELEMS = 4 * 32 * 4 * 47;
constexpr int PREDS_OFF = F_ELEMS;                 // 24064
constexpr int RBCP_OFF = PREDS_OFF + 1024 * 256;   // rbc_part[64][32]
constexpr int W2P_OFF = RBCP_OFF + 2048;
constexpr int W3P_OFF = W2P_OFF + 32768;

typedef __attribute__((ext_vector_type(8))) short short8;
typedef __attribute__((ext_vector_type(4))) float f32x4;

__device__ __forceinline__ int rfl(int x) { return __builtin_amdgcn_readfirstlane(x); }
__device__ __forceinline__ unsigned short f2bf(float x) {  // RNE bf16
    unsigned u = __float_as_uint(x);
    u += 0x7FFF + ((u >> 16) & 1);
    return (unsigned short)(u >> 16);
}
__device__ __forceinline__ float bf2f(unsigned short h) {
    return __uint_as_float(((unsigned)h) << 16);
}

// ---------------- Kernel 0: conv1 tables + fc2/fc3 weight swizzle (merged) ----------------
// blocks 0..93: F[c][node][o][i] (24064). blocks 94..605: packed weights (131072 shorts).
__global__ void prep_all(const float* __restrict__ emb, const float* __restrict__ w1,
                         const float* __restrict__ fc2_w, const float* __restrict__ fc3_w,
                         float* __restrict__ F,
                         unsigned short* __restrict__ W2p, unsigned short* __restrict__ W3p) {
    int b = blockIdx.x;
    if (b < 94) {
        int idx = b * 256 + threadIdx.x;  // exact 24064
        int i = idx % 47;
        int o = (idx / 47) % 4;
        int node = (idx / (47 * 4)) % 32;
        int c = idx / (47 * 4 * 32);
        float acc = 0.f;
#pragma unroll
        for (int k = 0; k < 3; k++) acc += w1[(o * 4 + c) * 3 + k] * emb[node * 96 + 2 * i + k];
        F[idx] = acc;
        return;
    }
    int t = (b - 94) * 256 + threadIdx.x;  // 131072 total
    if (t < 65536) {
        int j = t & 7, lane = (t >> 3) & 63, term = (t >> 9) & 1, ks = (t >> 10) & 3, nt = t >> 12;
        int k = ks * 32 + (lane >> 4) * 8 + j, n = nt * 16 + (lane & 15);
        float w = fc2_w[k * 256 + n];
        unsigned short hi = f2bf(w);
        W2p[t] = (term == 0) ? hi : f2bf(w - bf2f(hi));
    } else {
        int t3 = t - 65536;
        int j = t3 & 7, lane = (t3 >> 3) & 63, term = (t3 >> 9) & 1, ks = (t3 >> 10) & 7, nt = t3 >> 13;
        int k = ks * 32 + (lane >> 4) * 8 + j, n = nt * 16 + (lane & 15);
        float w = fc3_w[k * 128 + n];
        unsigned short hi = f2bf(w);
        W3p[t3] = (term == 0) ? hi : f2bf(w - bf2f(hi));
    }
}

// ---------------- Kernel 1: conv (VALU) + fc1 (VALU) + fc2/fc3 (MFMA bf16 hi/lo) ----------------
// LDS 51200 B -> 3 blocks/CU. X2/X3 in [kchunk][quad][m][8] layout: all LDS traffic is b128.
__global__ __launch_bounds__(256, 3)
void mlp_kernel(const float* __restrict__ F, const int* __restrict__ edges,
                const float* __restrict__ b1v,
                const float* __restrict__ w2, const float* __restrict__ b2,
                const float* __restrict__ w3, const float* __restrict__ b3,
                const float* __restrict__ fc1_w, const float* __restrict__ fc1_b,
                const float* __restrict__ fc2_b,
                const float* __restrict__ fc3_b,
                const float* __restrict__ fc4_w, const float* __restrict__ fc4_b,
                const unsigned short* __restrict__ W2p, const unsigned short* __restrict__ W3p,
                float* __restrict__ preds) {
    // LDS (floats), total 12800 = 51200 B:
    //  [0,8448): h1t [23][4][64] (5888) + h2t [10][4][64] at 5888
    //            flat_t [16][64] aliases [0,1024) during conv3/fc1 (h1t dead)
    //            X3 bf16 [8ks][4q][64m][8] = 16384 shorts aliases [0,8192) after fc2
    //  [8448,8704): part[256]
    //  [8704,12800): X2 bf16 [4ks][4q][64m][8] = 8192 shorts
    __shared__ __align__(16) float smem[12800];
    float* h1t = smem;
    float* h2t = smem + 5888;
    float* flat_t = smem;                           // alias h1t head
    float* part = smem + 8448;
    unsigned short* X3 = (unsigned short*)smem;     // [0,8192) floats
    unsigned short* X2 = (unsigned short*)(smem + 8704);

    const int tid = threadIdx.x;
    const int p = blockIdx.x >> 2;
    const int e0 = (blockIdx.x & 3) * 64;
    const int s = p >> 5, t = p & 31;
    if (s == t) return;

    // ---- conv1 (table sum) + pool ----
    {
        const int sample = tid >> 2, o = tid & 3;
        const int e = e0 + sample;
        const int u = edges[2 * e], v = edges[2 * e + 1];
        const float* F0 = F + ((0 * 32 + s) * 4 + o) * 47;
        const float* F1 = F + ((1 * 32 + t) * 4 + o) * 47;
        const float* F2 = F + ((2 * 32 + u) * 4 + o) * 47;
        const float* F3 = F + ((3 * 32 + v) * 4 + o) * 47;
        const float bb = b1v[o];
        float pre[46];
#pragma unroll
        for (int i = 0; i < 46; i++) {
            float x = F0[i] + F1[i] + F2[i] + F3[i] + bb;
            pre[i] = fmaxf(x, 0.f);
        }
#pragma unroll
        for (int j = 0; j < 23; j++)
            h1t[(j * 4 + o) * 64 + sample] = fmaxf(pre[2 * j], pre[2 * j + 1]);
    }
    __syncthreads();
    // ---- conv2 + pool (sliding window) ----
    {
        const int sample = tid >> 2, o = tid & 3;
        float wreg[12];
#pragma unroll
        for (int q = 0; q < 12; q++) wreg[q] = w2[o * 12 + q];
        const float bb = b2[o];
        float win[4][3];
#pragma unroll
        for (int c = 0; c < 4; c++) {
            win[c][0] = h1t[(0 * 4 + c) * 64 + sample];
            win[c][1] = h1t[(1 * 4 + c) * 64 + sample];
        }
        float pre[20];
#pragma unroll
        for (int i = 0; i < 20; i++) {
#pragma unroll
            for (int c = 0; c < 4; c++)
                win[c][(i + 2) % 3] = h1t[((i + 2) * 4 + c) * 64 + sample];
            float acc = bb;
#pragma unroll
            for (int c = 0; c < 4; c++)
#pragma unroll
                for (int k = 0; k < 3; k++)
                    acc = fmaf(wreg[c * 3 + k], win[c][(i + k) % 3], acc);
            pre[i] = fmaxf(acc, 0.f);
        }
#pragma unroll
        for (int j = 0; j < 10; j++)
            h2t[(j * 4 + o) * 64 + sample] = fmaxf(pre[2 * j], pre[2 * j + 1]);
    }
    __syncthreads();
    // ---- conv3 + pool + flatten (flat_t aliases dead h1t head) ----
    {
        const int sample = tid >> 2, o = tid & 3;
        float wreg[12];
#pragma unroll
        for (int q = 0; q < 12; q++) wreg[q] = w3[o * 12 + q];
        const float bb = b3[o];
        float win[4][3];
#pragma unroll
        for (int c = 0; c < 4; c++) {
            win[c][0] = h2t[(0 * 4 + c) * 64 + sample];
            win[c][1] = h2t[(1 * 4 + c) * 64 + sample];
        }
        float pre[8];
#pragma unroll
        for (int i = 0; i < 8; i++) {
#pragma unroll
            for (int c = 0; c < 4; c++)
                win[c][(i + 2) % 3] = h2t[((i + 2) * 4 + c) * 64 + sample];
            float acc = bb;
#pragma unroll
            for (int c = 0; c < 4; c++)
#pragma unroll
                for (int k = 0; k < 3; k++)
                    acc = fmaf(wreg[c * 3 + k], win[c][(i + k) % 3], acc);
            pre[i] = fmaxf(acc, 0.f);
        }
#pragma unroll
        for (int l = 0; l < 4; l++)
            flat_t[(o * 4 + l) * 64 + sample] = fmaxf(pre[2 * l], pre[2 * l + 1]);
    }
    __syncthreads();
    // ---- fc1: 16 -> 128 (VALU); pack bf16 X2 via 4x ds_write_b128 ----
    {
        const int lane = tid & 63, wave = tid >> 6;
        const int j0 = rfl(wave * 32);  // k-range [wave*32, wave*32+32) -> ks = wave
        float acc[32];
        const float* bp = fc1_b + j0;
#pragma unroll
        for (int jj = 0; jj < 32; jj++) acc[jj] = bp[jj];
#pragma unroll
        for (int kk = 0; kk < 16; kk++) {
            float a = flat_t[kk * 64 + lane];
            const float* wr = fc1_w + kk * 128 + j0;
#pragma unroll
            for (int jj = 0; jj < 32; jj++) acc[jj] = fmaf(a, wr[jj], acc[jj]);
        }
#pragma unroll
        for (int qk = 0; qk < 4; qk++) {
            short8 v;
#pragma unroll
            for (int j = 0; j < 8; j++) v[j] = (short)f2bf(fmaxf(acc[qk * 8 + j], 0.f));
            *(short8*)(X2 + ((wave * 4 + qk) * 64 + lane) * 8) = v;
        }
    }
    __syncthreads();
    // ---- fc2: [64x128] @ [128x256] MFMA; wave owns Ntiles 4w..4w+3 ----
    {
        const int lane = tid & 63, wave = tid >> 6;
        const int mrow = lane & 15, quad = lane >> 4;
        short8 afr[4][4];
#pragma unroll
        for (int mt = 0; mt < 4; mt++)
#pragma unroll
            for (int ks = 0; ks < 4; ks++)
                afr[mt][ks] = *(const short8*)(X2 + ((ks * 4 + quad) * 64 + mt * 16 + mrow) * 8);
        f32x4 acc[4][4];  // [ntl][mt]
#pragma unroll
        for (int a = 0; a < 4; a++)
#pragma unroll
            for (int b = 0; b < 4; b++) acc[a][b] = (f32x4){0.f, 0.f, 0.f, 0.f};
        const short8* W2v = (const short8*)W2p;
#pragma unroll
        for (int ntl = 0; ntl < 4; ntl++) {
            const int nt = wave * 4 + ntl;
#pragma unroll
            for (int ks = 0; ks < 4; ks++) {
                short8 bh = W2v[((nt * 4 + ks) * 2 + 0) * 64 + lane];
                short8 bl = W2v[((nt * 4 + ks) * 2 + 1) * 64 + lane];
#pragma unroll
                for (int mt = 0; mt < 4; mt++) {
                    acc[ntl][mt] = __builtin_amdgcn_mfma_f32_16x16x32_bf16(afr[mt][ks], bh, acc[ntl][mt], 0, 0, 0);
                    acc[ntl][mt] = __builtin_amdgcn_mfma_f32_16x16x32_bf16(afr[mt][ks], bl, acc[ntl][mt], 0, 0, 0);
                }
            }
        }
        __syncthreads();  // conv region + flat_t dead; X3 writes safe
        // epilogue: bias+relu -> X3[(n>>5,(n>>3)&3)][m][n&7]
#pragma unroll
        for (int ntl = 0; ntl < 4; ntl++) {
            const int n = (wave * 4 + ntl) * 16 + mrow;
            const float bias = fc2_b[n];
            const int kblk = ((n >> 5) * 4 + ((n >> 3) & 3));
            const int jn = n & 7;
#pragma unroll
            for (int mt = 0; mt < 4; mt++)
#pragma unroll
                for (int r = 0; r < 4; r++) {
                    const int m = mt * 16 + quad * 4 + r;
                    X3[(kblk * 64 + m) * 8 + jn] = f2bf(fmaxf(acc[ntl][mt][r] + bias, 0.f));
                }
        }
    }
    __syncthreads();
    // ---- fc3: [64x256] @ [256x128] MFMA; wave owns Ntiles 2w,2w+1; fc4 fused ----
    {
        const int lane = tid & 63, wave = tid >> 6;
        const int mrow = lane & 15, quad = lane >> 4;
        const short8* W3v = (const short8*)W3p;
        float p4[4][4];
#pragma unroll
        for (int a = 0; a < 4; a++)
#pragma unroll
            for (int b = 0; b < 4; b++) p4[a][b] = 0.f;
#pragma unroll
        for (int ntl = 0; ntl < 2; ntl++) {
            const int nt = wave * 2 + ntl;
            short8 B3h[8], B3l[8];
#pragma unroll
            for (int ks = 0; ks < 8; ks++) {
                B3h[ks] = W3v[((nt * 8 + ks) * 2 + 0) * 64 + lane];
                B3l[ks] = W3v[((nt * 8 + ks) * 2 + 1) * 64 + lane];
            }
            const int n = nt * 16 + mrow;
            const float bias = fc3_b[n];
            const float w4 = fc4_w[n];
#pragma unroll
            for (int mt = 0; mt < 4; mt++) {
                f32x4 acc3 = (f32x4){0.f, 0.f, 0.f, 0.f};
#pragma unroll
                for (int ks = 0; ks < 8; ks++) {
                    short8 a3 = *(const short8*)(X3 + ((ks * 4 + quad) * 64 + mt * 16 + mrow) * 8);
                    acc3 = __builtin_amdgcn_mfma_f32_16x16x32_bf16(a3, B3h[ks], acc3, 0, 0, 0);
                    acc3 = __builtin_amdgcn_mfma_f32_16x16x32_bf16(a3, B3l[ks], acc3, 0, 0, 0);
                }
#pragma unroll
                for (int r = 0; r < 4; r++)
                    p4[mt][r] = fmaf(fmaxf(acc3[r] + bias, 0.f), w4, p4[mt][r]);
            }
        }
#pragma unroll
        for (int mask = 1; mask < 16; mask <<= 1)
#pragma unroll
            for (int mt = 0; mt < 4; mt++)
#pragma unroll
                for (int r = 0; r < 4; r++)
                    p4[mt][r] += __shfl_xor(p4[mt][r], mask, 64);
        if ((lane & 15) == 0) {
#pragma unroll
            for (int mt = 0; mt < 4; mt++)
#pragma unroll
                for (int r = 0; r < 4; r++)
                    part[wave * 64 + mt * 16 + quad * 4 + r] = p4[mt][r];
        }
    }
    __syncthreads();
    if (tid < 64) {
        float pred = part[tid] + part[64 + tid] + part[128 + tid] + part[192 + tid] + fc4_b[0];
        preds[p * 256 + e0 + tid] = pred;
    }
}

// ---------------- Kernel 2: 3-step propagation; scatter to 64 slots ----------------
__global__ void prop_kernel(const int* __restrict__ edges,
                            const float* __restrict__ preds,
                            float* __restrict__ rbc_part) {
    const int p = blockIdx.x;
    const int s = p >> 5, t = p & 31;
    if (s == t) return;
    __shared__ float x[32], xn[32], racc[32];
    const int tid = threadIdx.x;
    if (tid < 32) { x[tid] = (tid == s) ? 1.f : 0.f; racc[tid] = 0.f; }
    const int u = edges[2 * tid], v = edges[2 * tid + 1];
    const float pr = preds[p * 256 + tid];
    for (int step = 0; step < 3; step++) {
        if (tid < 32) xn[tid] = 0.f;
        __syncthreads();
        atomicAdd(&xn[v], x[u] * pr);
        __syncthreads();
        if (tid < 32) { racc[tid] += xn[tid]; x[tid] = xn[tid]; }
        __syncthreads();
    }
    if (tid < 32) atomicAdd(&rbc_part[(p & 63) * 32 + tid], racc[tid]);
}

// ---------------- Kernel 3: reduce 64 slots + normalize ----------------
__global__ void norm_kernel(const float* __restrict__ rbc_part, float* __restrict__ out) {
    int lane = threadIdx.x;  // 64 threads
    float v = 0.f;
    if (lane < 32) {
#pragma unroll 8
        for (int s = 0; s < 64; s++) v += rbc_part[s * 32 + lane];
    }
    float tot = v;
#pragma unroll
    for (int mask = 1; mask < 32; mask <<= 1) tot += __shfl_xor(tot, mask, 32);
    if (lane < 32) out[lane] = v / tot;
}

extern "C" void kernel_launch(void* const* d_in, const int* in_sizes, int n_in,
                              void* d_out, int out_size, void* d_ws, size_t ws_size,
                              hipStream_t stream) {
    const float* emb = (const float*)d_in[0];
    const int* edges = (const int*)d_in[1];
    const float* w1 = (const float*)d_in[2];
    const float* b1 = (const float*)d_in[3];
    const float* w2 = (const float*)d_in[4];
    const float* b2 = (const float*)d_in[5];
    const float* w3 = (const float*)d_in[6];
    const float* b3 = (const float*)d_in[7];
    const float* fc1_w = (const float*)d_in[8];
    const float* fc1_b = (const float*)d_in[9];
    const float* fc2_w = (const float*)d_in[10];
    const float* fc2_b = (const float*)d_in[11];
    const float* fc3_w = (const float*)d_in[12];
    const float* fc3_b = (const float*)d_in[13];
    const float* fc4_w = (const float*)d_in[14];
    const float* fc4_b = (const float*)d_in[15];

    float* ws = (float*)d_ws;
    float* F = ws;
    float* preds = ws + PREDS_OFF;
    float* rbc_part = ws + RBCP_OFF;
    unsigned short* W2p = (unsigned short*)(ws + W2P_OFF);
    unsigned short* W3p = (unsigned short*)(ws + W3P_OFF);
    float* out = (float*)d_out;

    (void)hipMemsetAsync(rbc_part, 0, 2048 * sizeof(float), stream);
    prep_all<<<dim3(606), dim3(256), 0, stream>>>(emb, w1, fc2_w, fc3_w, F, W2p, W3p);
    mlp_kernel<<<dim3(4096), dim3(256), 0, stream>>>(
        F, edges, b1, w2, b2, w3, b3, fc1_w, fc1_b, fc2_b, fc3_b,
        fc4_w, fc4_b, W2p, W3p, preds);
    prop_kernel<<<dim3(1024), dim3(256), 0, stream>>>(edges, preds, rbc_part);
    norm_kernel<<<dim3(1), dim3(64), 0, stream>>>(rbc_part, out);
}